// Round 6
// baseline (216.319 us; speedup 1.0000x reference)
//
#include <hip/hip_runtime.h>

#define LR_C 0.01f
#define NB 8
#define NTOK 1024
#define DD 256
#define CH 8
#define NCHUNK (NTOK / CH)   // 128

// DPP add: s += dpp_move(s, ctrl), bound_ctrl=true
#define DPP_ADD(x, ctrl) \
    ((x) + __int_as_float(__builtin_amdgcn_update_dpp( \
        0, __float_as_int(x), (ctrl), 0xF, 0xF, true)))

// Full 64-lane all-lanes sum (gram kernel only).
#define REDUCE_ALL64(s) do { \
    s = DPP_ADD(s, 0xB1); \
    s = DPP_ADD(s, 0x4E); \
    s = DPP_ADD(s, 0x141); \
    s = DPP_ADD(s, 0x140); \
    s += __shfl_xor(s, 16, 64); \
    s += __shfl_xor(s, 32, 64); \
} while (0)

// Async global->LDS staging (no VGPR round-trip, can't be reg-sunk).
__device__ __forceinline__ void gload16(const float* g, float* l) {
    __builtin_amdgcn_global_load_lds(
        (const __attribute__((address_space(1))) unsigned int*)g,
        (__attribute__((address_space(3))) unsigned int*)l, 16, 0, 0);
}
__device__ __forceinline__ void gload4(const float* g, float* l) {
    __builtin_amdgcn_global_load_lds(
        (const __attribute__((address_space(1))) unsigned int*)g,
        (__attribute__((address_space(3))) unsigned int*)l, 4, 0, 0);
}

// ---------------------------------------------------------------------------
// GEMM1: C[m][n] = sum_k A[m][k]*B[n][k]. 128x64 tile, BK=16, 512 thr,
// 4x4/thread, reg-prefetch dbuf. grid (64,4) = 256 blocks, 2 waves/SIMD.
// ---------------------------------------------------------------------------
#define GM 128
#define GN 64
#define GK 16

__global__ __launch_bounds__(512) void gemm_abt_kernel(
    const float* __restrict__ A, const float* __restrict__ B,
    float* __restrict__ C)
{
    __shared__ float As[GK][GM + 4];
    __shared__ float Bs[GK][GN + 4];
    const int t    = threadIdx.x;
    const int arow = t >> 2, ak = (t & 3) * 4;   // 128 rows x 16 k
    const int brow = t >> 2, bk = (t & 3) * 4;   // t<256: 64 rows x 16 k
    const int tx   = t & 15, ty = t >> 4;        // ty 0..31

    const float* Ap = A + (size_t)(blockIdx.x * GM + arow) * DD + ak;
    const float* Bp = B + (size_t)(blockIdx.y * GN + (t < 256 ? brow : 0)) * DD + bk;

    float4 acc[4];
    #pragma unroll
    for (int i = 0; i < 4; ++i) acc[i] = make_float4(0.f, 0.f, 0.f, 0.f);

    float4 a0 = *reinterpret_cast<const float4*>(Ap);
    float4 b0 = *reinterpret_cast<const float4*>(Bp);

    for (int k0 = 0; k0 < DD; k0 += GK) {
        __syncthreads();
        As[ak + 0][arow] = a0.x; As[ak + 1][arow] = a0.y;
        As[ak + 2][arow] = a0.z; As[ak + 3][arow] = a0.w;
        if (t < 256) {
            Bs[bk + 0][brow] = b0.x; Bs[bk + 1][brow] = b0.y;
            Bs[bk + 2][brow] = b0.z; Bs[bk + 3][brow] = b0.w;
        }
        __syncthreads();
        if (k0 + GK < DD) {
            a0 = *reinterpret_cast<const float4*>(Ap + k0 + GK);
            b0 = *reinterpret_cast<const float4*>(Bp + k0 + GK);
        }
        #pragma unroll
        for (int k = 0; k < GK; ++k) {
            float4 av = *reinterpret_cast<const float4*>(&As[k][ty * 4]);
            float4 bv = *reinterpret_cast<const float4*>(&Bs[k][tx * 4]);
            acc[0].x = fmaf(av.x, bv.x, acc[0].x); acc[0].y = fmaf(av.x, bv.y, acc[0].y);
            acc[0].z = fmaf(av.x, bv.z, acc[0].z); acc[0].w = fmaf(av.x, bv.w, acc[0].w);
            acc[1].x = fmaf(av.y, bv.x, acc[1].x); acc[1].y = fmaf(av.y, bv.y, acc[1].y);
            acc[1].z = fmaf(av.y, bv.z, acc[1].z); acc[1].w = fmaf(av.y, bv.w, acc[1].w);
            acc[2].x = fmaf(av.z, bv.x, acc[2].x); acc[2].y = fmaf(av.z, bv.y, acc[2].y);
            acc[2].z = fmaf(av.z, bv.z, acc[2].z); acc[2].w = fmaf(av.z, bv.w, acc[2].w);
            acc[3].x = fmaf(av.w, bv.x, acc[3].x); acc[3].y = fmaf(av.w, bv.y, acc[3].y);
            acc[3].z = fmaf(av.w, bv.z, acc[3].z); acc[3].w = fmaf(av.w, bv.w, acc[3].w);
        }
    }
    #pragma unroll
    for (int i = 0; i < 4; ++i) {
        float* cp = C + (size_t)(blockIdx.x * GM + ty * 4 + i) * DD
                      + blockIdx.y * GN + tx * 4;
        *reinterpret_cast<float4*>(cp) = acc[i];
    }
}

// ---------------------------------------------------------------------------
// GEMM2: C[b*1024+t][n] = sum_k PT[b][k][t]*B[n][k]. PT is [NB][DD][NTOK].
// Same 128x64 structure; A-tile loads contiguous in t.
// ---------------------------------------------------------------------------
__global__ __launch_bounds__(512) void gemm_pt_kernel(
    const float* __restrict__ PT, const float* __restrict__ B,
    float* __restrict__ C)
{
    __shared__ float As[GK][GM + 4];
    __shared__ float Bs[GK][GN + 4];
    const int t  = threadIdx.x;
    const int mb = blockIdx.x;               // 0..63
    const int b  = mb >> 3;                  // 8 m-tiles per batch
    const int t0 = (mb & 7) * GM;

    const int krow = t >> 5, tcol = (t & 31) * 4;     // 16 k x 128 t
    const int brow = t >> 2, bk   = (t & 3) * 4;
    const int tx   = t & 15, ty   = t >> 4;

    const float* Ap = PT + (size_t)b * DD * NTOK + (size_t)krow * NTOK + t0 + tcol;
    const float* Bp = B + (size_t)(blockIdx.y * GN + (t < 256 ? brow : 0)) * DD + bk;

    float4 acc[4];
    #pragma unroll
    for (int i = 0; i < 4; ++i) acc[i] = make_float4(0.f, 0.f, 0.f, 0.f);

    float4 a0 = *reinterpret_cast<const float4*>(Ap);
    float4 b0 = *reinterpret_cast<const float4*>(Bp);

    for (int k0 = 0; k0 < DD; k0 += GK) {
        __syncthreads();
        *reinterpret_cast<float4*>(&As[krow][tcol]) = a0;
        if (t < 256) {
            Bs[bk + 0][brow] = b0.x; Bs[bk + 1][brow] = b0.y;
            Bs[bk + 2][brow] = b0.z; Bs[bk + 3][brow] = b0.w;
        }
        __syncthreads();
        if (k0 + GK < DD) {
            a0 = *reinterpret_cast<const float4*>(Ap + (size_t)(k0 + GK) * NTOK);
            b0 = *reinterpret_cast<const float4*>(Bp + k0 + GK);
        }
        #pragma unroll
        for (int k = 0; k < GK; ++k) {
            float4 av = *reinterpret_cast<const float4*>(&As[k][ty * 4]);
            float4 bv = *reinterpret_cast<const float4*>(&Bs[k][tx * 4]);
            acc[0].x = fmaf(av.x, bv.x, acc[0].x); acc[0].y = fmaf(av.x, bv.y, acc[0].y);
            acc[0].z = fmaf(av.x, bv.z, acc[0].z); acc[0].w = fmaf(av.x, bv.w, acc[0].w);
            acc[1].x = fmaf(av.y, bv.x, acc[1].x); acc[1].y = fmaf(av.y, bv.y, acc[1].y);
            acc[1].z = fmaf(av.y, bv.z, acc[1].z); acc[1].w = fmaf(av.y, bv.w, acc[1].w);
            acc[2].x = fmaf(av.z, bv.x, acc[2].x); acc[2].y = fmaf(av.z, bv.y, acc[2].y);
            acc[2].z = fmaf(av.z, bv.z, acc[2].z); acc[2].w = fmaf(av.z, bv.w, acc[2].w);
            acc[3].x = fmaf(av.w, bv.x, acc[3].x); acc[3].y = fmaf(av.w, bv.y, acc[3].y);
            acc[3].z = fmaf(av.w, bv.z, acc[3].z); acc[3].w = fmaf(av.w, bv.w, acc[3].w);
        }
    }
    #pragma unroll
    for (int i = 0; i < 4; ++i) {
        float* cp = C + (size_t)(b * NTOK + t0 + ty * 4 + i) * DD
                      + blockIdx.y * GN + tx * 4;
        *reinterpret_cast<float4*>(cp) = acc[i];
    }
}

// ---------------------------------------------------------------------------
// Gram: c_ij = h_i . h_j for j<i in chunk of 8 (unchanged; passed R4/R5).
// ---------------------------------------------------------------------------
__global__ __launch_bounds__(128) void gram_kernel(
    const float* __restrict__ H, float* __restrict__ Gram)
{
    const int blk  = blockIdx.x;
    const int b    = blk & 7;
    const int chk  = blk >> 3;
    const int w    = threadIdx.x >> 6;
    const int lane = threadIdx.x & 63;
    const float* Hc = H + ((size_t)b * NTOK + (size_t)chk * CH) * DD + lane * 4;

    float4 h[CH];
    #pragma unroll
    for (int i = 0; i < CH; ++i)
        h[i] = *reinterpret_cast<const float4*>(Hc + (size_t)i * DD);

    float sel = 0.f;
    #pragma unroll
    for (int i = 1; i < CH; ++i) {
        #pragma unroll
        for (int j = 0; j < i; ++j) {
            const int idx = i * (i - 1) / 2 + j;
            if ((idx & 1) == w) {
                float s = h[j].x * h[i].x;
                s = fmaf(h[j].y, h[i].y, s);
                s = fmaf(h[j].z, h[i].z, s);
                s = fmaf(h[j].w, h[i].w, s);
                REDUCE_ALL64(s);
                sel = (lane == idx) ? s : sel;
            }
        }
    }
    if (lane < 28 && (lane & 1) == w)
        Gram[((size_t)b * NCHUNK + chk) * 32 + lane] = sel;
}

// ---------------------------------------------------------------------------
// Chunked scan. Block = 256 thr = 4 waves = 4 rows of one batch (XCD-swizzled).
// LDS-pipelined: per chunk, __syncthreads (vmcnt(0)+barrier = wait for last
// stage) -> issue async stage of chunk+1 -> compute chunk from LDS.
// Reduce via LDS transpose (8 partials -> 8 totals in ~28 ops).
// ---------------------------------------------------------------------------
__global__ __launch_bounds__(256, 2) void theta_scan_kernel(
    const float* __restrict__ H, const float* __restrict__ Tgt,
    const float* __restrict__ theta0, const float* __restrict__ Gram,
    float* __restrict__ PT)
{
    __shared__ float Hbuf[2][CH][DD];   // 16 KB
    __shared__ float Scr[4][CH][64];    // 8 KB
    __shared__ float TGb[2][64];        // 512 B
    __shared__ float GRb[2][64];        // 512 B

    const int b    = blockIdx.x & 7;     // batch -> XCD
    const int rb   = blockIdx.x >> 3;    // 64 row-quads
    const int wid  = threadIdx.x >> 6;
    const int lane = threadIdx.x & 63;
    const int row  = rb * 4 + wid;

    float4 th = *reinterpret_cast<const float4*>(
        theta0 + (size_t)row * DD + lane * 4);

    const float* Hb = H   + (size_t)b * NTOK * DD;
    const float* Tb = Tgt + (size_t)b * NTOK * DD;
    const float* Gb = Gram + (size_t)b * NCHUNK * 32;
    float*       Pb = PT  + ((size_t)b * DD + row) * NTOK;

    const int ll = lane & 31;          // duplicated lanes 32..63 (no exec mask)
    const int tt = ll & 7, rr = ll >> 3;

    // ---- prologue: stage chunk 0 into parity 0 ----
    {
        const float* g0 = Hb + (size_t)(2 * wid) * DD + lane * 4;
        gload16(g0,      &Hbuf[0][2 * wid][0]);
        gload16(g0 + DD, &Hbuf[0][2 * wid + 1][0]);
        if (wid == 0)
            gload4(Tb + (size_t)tt * DD + rb * 4 + rr, &TGb[0][0]);
        if (wid == 1)
            gload4(Gb + ll, &GRb[0][0]);
    }

    for (int ch = 0; ch < NCHUNK; ++ch) {
        const int par = ch & 1;
        __syncthreads();   // vmcnt(0)+barrier: chunk ch staged & visible

        if (ch + 1 < NCHUNK) {         // stage chunk ch+1 into parity par^1
            const int np = par ^ 1;
            const float* g0 = Hb + (size_t)((ch + 1) * CH + 2 * wid) * DD + lane * 4;
            gload16(g0,      &Hbuf[np][2 * wid][0]);
            gload16(g0 + DD, &Hbuf[np][2 * wid + 1][0]);
            if (wid == 0)
                gload4(Tb + (size_t)((ch + 1) * CH + tt) * DD + rb * 4 + rr,
                       &TGb[np][0]);
            if (wid == 1)
                gload4(Gb + (ch + 1) * 32 + ll, &GRb[np][0]);
        }

        // ---- partial dots ----
        float4 hh[CH]; float s[CH];
        #pragma unroll
        for (int i = 0; i < CH; ++i) {
            hh[i] = *reinterpret_cast<const float4*>(&Hbuf[par][i][lane * 4]);
            float sv = hh[i].x * th.x;
            sv = fmaf(hh[i].y, th.y, sv);
            sv = fmaf(hh[i].z, th.z, sv);
            sv = fmaf(hh[i].w, th.w, sv);
            s[i] = sv;
        }
        // ---- LDS transpose reduce: 8x64 partials -> 8 totals ----
        #pragma unroll
        for (int i = 0; i < CH; ++i) Scr[wid][i][lane] = s[i];
        const float* sb = &Scr[wid][0][0];
        float4 r0 = *reinterpret_cast<const float4*>(sb + lane * 8);
        float4 r1 = *reinterpret_cast<const float4*>(sb + lane * 8 + 4);
        float sum = ((r0.x + r0.y) + (r0.z + r0.w))
                  + ((r1.x + r1.y) + (r1.z + r1.w));
        sum = DPP_ADD(sum, 0xB1);    // xor1
        sum = DPP_ADD(sum, 0x4E);    // xor2
        sum = DPP_ADD(sum, 0x141);   // xor4 (row_half_mirror)
        float a[CH];
        #pragma unroll
        for (int i = 0; i < CH; ++i)
            a[i] = __int_as_float(
                __builtin_amdgcn_readlane(__float_as_int(sum), 8 * i));

        // ---- tgt + gram from LDS ----
        const float4* tb4 = reinterpret_cast<const float4*>(&TGb[par][wid * 8]);
        float4 tg0 = tb4[0], tg1 = tb4[1];
        float lt[CH] = {LR_C * tg0.x, LR_C * tg0.y, LR_C * tg0.z, LR_C * tg0.w,
                        LR_C * tg1.x, LR_C * tg1.y, LR_C * tg1.z, LR_C * tg1.w};
        const float4* gb4 = reinterpret_cast<const float4*>(&GRb[par][0]);
        float gv[28];
        #pragma unroll
        for (int q = 0; q < 7; ++q)
            *reinterpret_cast<float4*>(&gv[q * 4]) = gb4[q];

        // ---- serial fixup (compile-time indices) ----
        float e[CH], p[CH];
        #pragma unroll
        for (int i = 0; i < CH; ++i) {
            float pv = a[i];
            #pragma unroll
            for (int j = 0; j < i; ++j)
                pv = fmaf(e[j], gv[i * (i - 1) / 2 + j], pv);
            p[i] = pv;
            e[i] = fmaf(-LR_C, pv, lt[i]);
        }
        // ---- theta update ----
        #pragma unroll
        for (int j = 0; j < CH; ++j) {
            th.x = fmaf(e[j], hh[j].x, th.x);
            th.y = fmaf(e[j], hh[j].y, th.y);
            th.z = fmaf(e[j], hh[j].z, th.z);
            th.w = fmaf(e[j], hh[j].w, th.w);
        }
        // ---- store predictions (transposed) ----
        float sel = p[0];
        #pragma unroll
        for (int i = 1; i < CH; ++i) sel = (lane == i) ? p[i] : sel;
        if (lane < CH) Pb[ch * CH + lane] = sel;
    }
}

// ---------------------------------------------------------------------------
extern "C" void kernel_launch(void* const* d_in, const int* in_sizes, int n_in,
                              void* d_out, int out_size, void* d_ws, size_t ws_size,
                              hipStream_t stream) {
    const float* seq    = (const float*)d_in[0];
    const float* tgt    = (const float*)d_in[1];
    const float* theta0 = (const float*)d_in[2];
    const float* W_e    = (const float*)d_in[3];
    const float* W_o    = (const float*)d_in[4];
    float* out = (float*)d_out;

    float* Hbuf  = (float*)d_ws;                      // 8 MB
    float* PTbuf = Hbuf + (size_t)NB * NTOK * DD;     // 8 MB, [NB][DD][NTOK]
    float* Cbuf  = out;                                // gram scratch (128 KB)

    dim3 ggrid(NB * NTOK / GM, DD / GN);              // (64, 4)

    gemm_abt_kernel<<<ggrid, 512, 0, stream>>>(seq, W_e, Hbuf);
    gram_kernel<<<NB * NCHUNK, 128, 0, stream>>>(Hbuf, Cbuf);
    theta_scan_kernel<<<NB * 64, 256, 0, stream>>>(Hbuf, tgt, theta0, Cbuf, PTbuf);
    gemm_pt_kernel<<<ggrid, 512, 0, stream>>>(PTbuf, W_o, out);
}